// Round 3
// baseline (1889.818 us; speedup 1.0000x reference)
//
#include <hip/hip_runtime.h>

#define FEAT 128

// ---------------- degree histogram ----------------
__global__ void k_count_deg(const int* __restrict__ ei, int E, int* __restrict__ deg) {
    int e = blockIdx.x * blockDim.x + threadIdx.x;
    if (e < E) atomicAdd(&deg[ei[E + e]], 1);
}

__global__ void k_dis(const int* __restrict__ deg, float* __restrict__ dis, int n) {
    int i = blockIdx.x * blockDim.x + threadIdx.x;
    if (i < n) dis[i] = rsqrtf((float)(1 + deg[i]));
}

// ---------------- single-block exclusive scan over deg -> row_ptr, cursor ----------------
__global__ void k_scan(const int* __restrict__ deg, int* __restrict__ row_ptr,
                       int* __restrict__ cursor, int n) {
    __shared__ int sums[1024];
    int tid = threadIdx.x;
    int chunk = (n + 1023) >> 10;
    int start = tid * chunk;
    int end = min(start + chunk, n);
    int s = 0;
    for (int i = start; i < end; ++i) s += deg[i];
    sums[tid] = s;
    __syncthreads();
    for (int off = 1; off < 1024; off <<= 1) {
        int v = (tid >= off) ? sums[tid - off] : 0;
        __syncthreads();
        sums[tid] += v;
        __syncthreads();
    }
    int run = (tid == 0) ? 0 : sums[tid - 1];
    for (int i = start; i < end; ++i) {
        row_ptr[i] = run;
        cursor[i] = run;
        run += deg[i];
    }
    if (tid == 1023) row_ptr[n] = sums[1023];
}

// ---------------- CSR fill: single 4B scatter per edge ----------------
__global__ void k_fill_csr(const int* __restrict__ ei, int E,
                           int* __restrict__ cursor,
                           int* __restrict__ csr_src) {
    int e = blockIdx.x * blockDim.x + threadIdx.x;
    if (e >= E) return;
    int s = ei[e], d = ei[E + e];
    int pos = atomicAdd(&cursor[d], 1);
    csr_src[pos] = s;
}

// ---------------- GEMM: out[n,128] = A[n,128] @ W[128,128] ----------------
__global__ __launch_bounds__(256) void k_gemm128(const float* __restrict__ A,
                                                 const float* __restrict__ W,
                                                 float* __restrict__ out, int n) {
    __shared__ float As[32][33];   // transposed A chunk: As[k][row]
    __shared__ float Ws[32][128];
    int tid = threadIdx.x;
    int row0b = blockIdx.x * 32;
    int cg = tid & 31, rg = tid >> 5;
    int col0 = cg * 4, r0 = rg * 4;
    float acc[4][4] = {};
    int ar = tid >> 3;
    int ak = (tid & 7) * 4;
    int grow = row0b + ar;
    for (int kc = 0; kc < 128; kc += 32) {
        float4 v = make_float4(0.f, 0.f, 0.f, 0.f);
        if (grow < n) v = *(const float4*)(A + (size_t)grow * FEAT + kc + ak);
        As[ak + 0][ar] = v.x; As[ak + 1][ar] = v.y;
        As[ak + 2][ar] = v.z; As[ak + 3][ar] = v.w;
#pragma unroll
        for (int j = 0; j < 4; ++j) {
            int idx = tid + j * 256;       // 1024 float4 slots
            int wk = idx >> 5;
            int wc = (idx & 31) * 4;
            *(float4*)&Ws[wk][wc] = *(const float4*)(W + (size_t)(kc + wk) * 128 + wc);
        }
        __syncthreads();
#pragma unroll
        for (int k = 0; k < 32; ++k) {
            float a0 = As[k][r0 + 0], a1 = As[k][r0 + 1];
            float a2 = As[k][r0 + 2], a3 = As[k][r0 + 3];
            float4 w = *(float4*)&Ws[k][col0];
            acc[0][0] += a0 * w.x; acc[0][1] += a0 * w.y; acc[0][2] += a0 * w.z; acc[0][3] += a0 * w.w;
            acc[1][0] += a1 * w.x; acc[1][1] += a1 * w.y; acc[1][2] += a1 * w.z; acc[1][3] += a1 * w.w;
            acc[2][0] += a2 * w.x; acc[2][1] += a2 * w.y; acc[2][2] += a2 * w.z; acc[2][3] += a2 * w.w;
            acc[3][0] += a3 * w.x; acc[3][1] += a3 * w.y; acc[3][2] += a3 * w.z; acc[3][3] += a3 * w.w;
        }
        __syncthreads();
    }
#pragma unroll
    for (int i = 0; i < 4; ++i) {
        int row = row0b + r0 + i;
        if (row < n)
            *(float4*)(out + (size_t)row * 128 + col0) =
                make_float4(acc[i][0], acc[i][1], acc[i][2], acc[i][3]);
    }
}

// ---------------- head GEMM: mu = A@Wmu + bmu, ls = A@Wls + bls ----------------
__global__ __launch_bounds__(256) void k_gemm_head(const float* __restrict__ A,
                                                   const float* __restrict__ Wmu,
                                                   const float* __restrict__ Wls,
                                                   const float* __restrict__ bmu,
                                                   const float* __restrict__ bls,
                                                   float* __restrict__ mu,
                                                   float* __restrict__ ls, int n) {
    __shared__ float As[32][33];
    __shared__ float Ws[32][128];  // cols 0..63 = Wmu, 64..127 = Wls
    int tid = threadIdx.x;
    int row0b = blockIdx.x * 32;
    int cg = tid & 31, rg = tid >> 5;
    int col0 = cg * 4, r0 = rg * 4;
    float acc[4][4] = {};
    int ar = tid >> 3;
    int ak = (tid & 7) * 4;
    int grow = row0b + ar;
    for (int kc = 0; kc < 128; kc += 32) {
        float4 v = make_float4(0.f, 0.f, 0.f, 0.f);
        if (grow < n) v = *(const float4*)(A + (size_t)grow * FEAT + kc + ak);
        As[ak + 0][ar] = v.x; As[ak + 1][ar] = v.y;
        As[ak + 2][ar] = v.z; As[ak + 3][ar] = v.w;
#pragma unroll
        for (int j = 0; j < 4; ++j) {
            int idx = tid + j * 256;
            int wk = idx >> 5;
            int wc = (idx & 31) * 4;
            const float* Wp = (wc < 64) ? (Wmu + (size_t)(kc + wk) * 64 + wc)
                                        : (Wls + (size_t)(kc + wk) * 64 + (wc - 64));
            *(float4*)&Ws[wk][wc] = *(const float4*)Wp;
        }
        __syncthreads();
#pragma unroll
        for (int k = 0; k < 32; ++k) {
            float a0 = As[k][r0 + 0], a1 = As[k][r0 + 1];
            float a2 = As[k][r0 + 2], a3 = As[k][r0 + 3];
            float4 w = *(float4*)&Ws[k][col0];
            acc[0][0] += a0 * w.x; acc[0][1] += a0 * w.y; acc[0][2] += a0 * w.z; acc[0][3] += a0 * w.w;
            acc[1][0] += a1 * w.x; acc[1][1] += a1 * w.y; acc[1][2] += a1 * w.z; acc[1][3] += a1 * w.w;
            acc[2][0] += a2 * w.x; acc[2][1] += a2 * w.y; acc[2][2] += a2 * w.z; acc[2][3] += a2 * w.w;
            acc[3][0] += a3 * w.x; acc[3][1] += a3 * w.y; acc[3][2] += a3 * w.z; acc[3][3] += a3 * w.w;
        }
        __syncthreads();
    }
    bool is_mu = (col0 < 64);
    const float* bp = is_mu ? (bmu + col0) : (bls + (col0 - 64));
    float4 b = *(const float4*)bp;
    float* op = is_mu ? mu : ls;
    int c = is_mu ? col0 : col0 - 64;
#pragma unroll
    for (int i = 0; i < 4; ++i) {
        int row = row0b + r0 + i;
        if (row < n)
            *(float4*)(op + (size_t)row * 64 + c) =
                make_float4(acc[i][0] + b.x, acc[i][1] + b.y, acc[i][2] + b.z, acc[i][3] + b.w);
    }
}

// ---------------- sliced aggregation: out = [relu](A_norm @ t + bias) ----------------
// slice = blockIdx.x & 7 -> XCD-pinned 16-col slice (3.2 MB, fits 4 MB per-XCD L2).
// wave = 1 node; quarter-wave (16 lanes) gathers one edge's 64B line.
__global__ __launch_bounds__(256) void k_agg_sliced(const float* __restrict__ t,
                                                    const int* __restrict__ row_ptr,
                                                    const int* __restrict__ csr_src,
                                                    const float* __restrict__ dis,
                                                    const float* __restrict__ bias,
                                                    float* __restrict__ out, int n, int do_relu) {
    int bid = blockIdx.x;
    int slice = bid & 7;          // -> XCD under round-robin dispatch
    int nb = bid >> 3;            // node-block of 4 nodes
    int wid = threadIdx.x >> 6;
    int lane = threadIdx.x & 63;
    int node = nb * 4 + wid;
    if (node >= n) return;
    int q = lane >> 4;            // quarter 0..3 (edge sub-index)
    int c = lane & 15;            // column within slice
    int col = slice * 16 + c;
    float d = dis[node];
    float acc = 0.f, acc2 = 0.f;
    int e = row_ptr[node], e1 = row_ptr[node + 1];
    // 8 edges per iteration (2 per quarter) for load-latency overlap
    for (; e + 7 < e1; e += 8) {
        int s0 = __builtin_nontemporal_load(csr_src + e + q);
        int s1 = __builtin_nontemporal_load(csr_src + e + 4 + q);
        float w0 = dis[s0] * d;
        float w1 = dis[s1] * d;
        float v0 = t[(size_t)s0 * FEAT + col];
        float v1 = t[(size_t)s1 * FEAT + col];
        acc  += w0 * v0;
        acc2 += w1 * v1;
    }
    if (e + 3 < e1) {
        int s0 = __builtin_nontemporal_load(csr_src + e + q);
        float w0 = dis[s0] * d;
        acc += w0 * t[(size_t)s0 * FEAT + col];
        e += 4;
    }
    if (e + q < e1) {
        int s0 = __builtin_nontemporal_load(csr_src + e + q);
        acc2 += dis[s0] * d * t[(size_t)s0 * FEAT + col];
    }
    acc += acc2;
    // reduce across quarters (lanes c, c+16, c+32, c+48)
    acc += __shfl_xor(acc, 16);
    acc += __shfl_xor(acc, 32);
    if (q == 0) {
        float v = acc + d * d * t[(size_t)node * FEAT + col];
        if (bias) v += bias[col];
        if (do_relu) v = fmaxf(v, 0.f);
        out[(size_t)node * FEAT + col] = v;
    }
}

extern "C" void kernel_launch(void* const* d_in, const int* in_sizes, int n_in,
                              void* d_out, int out_size, void* d_ws, size_t ws_size,
                              hipStream_t stream) {
    const float* x   = (const float*)d_in[0];
    const int*   ei  = (const int*)d_in[1];
    const float* W1  = (const float*)d_in[2];
    const float* b1  = (const float*)d_in[3];
    const float* W2  = (const float*)d_in[4];
    const float* b2  = (const float*)d_in[5];
    const float* W3  = (const float*)d_in[6];
    const float* b3  = (const float*)d_in[7];
    const float* Wmu = (const float*)d_in[8];
    const float* bmu = (const float*)d_in[9];
    const float* Wls = (const float*)d_in[10];
    const float* bls = (const float*)d_in[11];

    int n = in_sizes[0] / FEAT;    // 50000
    int E = in_sizes[1] / 2;       // 1,600,000

    char* ws = (char*)d_ws;
    size_t off = 0;
    auto alloc = [&](size_t bytes) {
        void* p = ws + off;
        off = (off + bytes + 255) & ~(size_t)255;
        return p;
    };
    float* Bt       = (float*)alloc((size_t)n * FEAT * 4);
    float* Bh       = (float*)alloc((size_t)n * FEAT * 4);
    int*   deg      = (int*)alloc((size_t)n * 4);
    float* dis      = (float*)alloc((size_t)n * 4);
    int*   row_ptr  = (int*)alloc((size_t)(n + 1) * 4);
    int*   cursor   = (int*)alloc((size_t)n * 4);
    int*   csr_src  = (int*)alloc((size_t)E * 4);

    hipMemsetAsync(deg, 0, (size_t)n * 4, stream);

    int eb = (E + 255) / 256;
    k_count_deg<<<eb, 256, 0, stream>>>(ei, E, deg);
    k_dis<<<(n + 255) / 256, 256, 0, stream>>>(deg, dis, n);
    k_scan<<<1, 1024, 0, stream>>>(deg, row_ptr, cursor, n);
    k_fill_csr<<<eb, 256, 0, stream>>>(ei, E, cursor, csr_src);

    int gb = (n + 31) / 32;
    int ab = ((n + 3) / 4) * 8;    // 8 XCD-pinned slices
    float* mu = (float*)d_out;
    float* ls = (float*)d_out + (size_t)n * 64;

    k_gemm128<<<gb, 256, 0, stream>>>(x,  W1, Bt, n);
    k_agg_sliced<<<ab, 256, 0, stream>>>(Bt, row_ptr, csr_src, dis, b1, Bh, n, 1);
    k_gemm128<<<gb, 256, 0, stream>>>(Bh, W2, Bt, n);
    k_agg_sliced<<<ab, 256, 0, stream>>>(Bt, row_ptr, csr_src, dis, b2, Bh, n, 1);
    k_gemm128<<<gb, 256, 0, stream>>>(Bh, W3, Bt, n);
    k_agg_sliced<<<ab, 256, 0, stream>>>(Bt, row_ptr, csr_src, dis, b3, Bh, n, 1);
    // g = A_norm @ h3 (shared by both heads; aggregation is linear)
    k_agg_sliced<<<ab, 256, 0, stream>>>(Bh, row_ptr, csr_src, dis, nullptr, Bt, n, 0);
    k_gemm_head<<<gb, 256, 0, stream>>>(Bt, Wmu, Wls, bmu, bls, mu, ls, n);
}

// Round 7
// 900.705 us; speedup vs baseline: 2.0982x; 2.0982x over previous
//
#include <hip/hip_runtime.h>

#define FEAT 128

// ---------------- degree histogram ----------------
__global__ void k_count_deg(const int* __restrict__ ei, int E, int* __restrict__ deg) {
    int e = blockIdx.x * blockDim.x + threadIdx.x;
    if (e < E) atomicAdd(&deg[ei[E + e]], 1);
}

__global__ void k_dis(const int* __restrict__ deg, float* __restrict__ dis, int n) {
    int i = blockIdx.x * blockDim.x + threadIdx.x;
    if (i < n) dis[i] = rsqrtf((float)(1 + deg[i]));
}

// ---------------- single-block exclusive scan over deg -> row_ptr, cursor ----------------
__global__ void k_scan(const int* __restrict__ deg, int* __restrict__ row_ptr,
                       int* __restrict__ cursor, int n) {
    __shared__ int sums[1024];
    int tid = threadIdx.x;
    int chunk = (n + 1023) >> 10;
    int start = tid * chunk;
    int end = min(start + chunk, n);
    int s = 0;
    for (int i = start; i < end; ++i) s += deg[i];
    sums[tid] = s;
    __syncthreads();
    for (int off = 1; off < 1024; off <<= 1) {
        int v = (tid >= off) ? sums[tid - off] : 0;
        __syncthreads();
        sums[tid] += v;
        __syncthreads();
    }
    int run = (tid == 0) ? 0 : sums[tid - 1];
    for (int i = start; i < end; ++i) {
        row_ptr[i] = run;
        cursor[i] = run;
        run += deg[i];
    }
    if (tid == 1023) row_ptr[n] = sums[1023];
}

// ---------------- CSR fill: ONE 8B scatter per edge (src + norm packed) ----------------
__global__ void k_fill_csr(const int* __restrict__ ei, int E,
                           const float* __restrict__ dis,
                           int* __restrict__ cursor,
                           int2* __restrict__ csr) {
    int e = blockIdx.x * blockDim.x + threadIdx.x;
    if (e >= E) return;
    int s = ei[e], d = ei[E + e];
    int pos = atomicAdd(&cursor[d], 1);
    csr[pos] = make_int2(s, __float_as_int(dis[s] * dis[d]));
}

// ---------------- GEMM: out[n,128] = A[n,128] @ W[128,128], 64x128 tile, 8x4/thread ----------------
__global__ __launch_bounds__(256) void k_gemm128(const float* __restrict__ A,
                                                 const float* __restrict__ W,
                                                 float* __restrict__ out, int n) {
    __shared__ float As[32][64];    // As[k][row]; bank = row%32 -> 2-way on store (free)
    __shared__ float Ws[32][128];
    int tid = threadIdx.x;
    int row0b = blockIdx.x * 64;
    int tx = tid & 31, ty = tid >> 5;
    int col0 = tx * 4, r0 = ty * 8;
    float4 acc[8];
#pragma unroll
    for (int i = 0; i < 8; ++i) acc[i] = make_float4(0.f, 0.f, 0.f, 0.f);

    // A staging: thread loads row r = tid&63, k-quads qk4 and qk4+16 (qk4 = (tid>>6)*4)
    int sr = tid & 63;
    int sq = (tid >> 6) * 4;
    int grow = row0b + sr;

    for (int kc = 0; kc < 128; kc += 32) {
#pragma unroll
        for (int j = 0; j < 2; ++j) {
            int qk = sq + j * 16;
            float4 v = make_float4(0.f, 0.f, 0.f, 0.f);
            if (grow < n) v = *(const float4*)(A + (size_t)grow * FEAT + kc + qk);
            As[qk + 0][sr] = v.x; As[qk + 1][sr] = v.y;
            As[qk + 2][sr] = v.z; As[qk + 3][sr] = v.w;
        }
#pragma unroll
        for (int j = 0; j < 4; ++j) {
            int idx = tid + j * 256;       // 1024 float4 slots
            int wk = idx >> 5;
            int wc = (idx & 31) * 4;
            *(float4*)&Ws[wk][wc] = *(const float4*)(W + (size_t)(kc + wk) * 128 + wc);
        }
        __syncthreads();
#pragma unroll
        for (int k = 0; k < 32; ++k) {
            float4 w = *(float4*)&Ws[k][col0];
            float a[8];
            *(float4*)&a[0] = *(float4*)&As[k][r0];
            *(float4*)&a[4] = *(float4*)&As[k][r0 + 4];
#pragma unroll
            for (int i = 0; i < 8; ++i) {
                acc[i].x += a[i] * w.x;
                acc[i].y += a[i] * w.y;
                acc[i].z += a[i] * w.z;
                acc[i].w += a[i] * w.w;
            }
        }
        __syncthreads();
    }
#pragma unroll
    for (int i = 0; i < 8; ++i) {
        int row = row0b + r0 + i;
        if (row < n)
            *(float4*)(out + (size_t)row * 128 + col0) = acc[i];
    }
}

// ---------------- head GEMM: [mu|ls] = A @ [Wmu|Wls] + [bmu|bls] ----------------
__global__ __launch_bounds__(256) void k_gemm_head(const float* __restrict__ A,
                                                   const float* __restrict__ Wmu,
                                                   const float* __restrict__ Wls,
                                                   const float* __restrict__ bmu,
                                                   const float* __restrict__ bls,
                                                   float* __restrict__ mu,
                                                   float* __restrict__ ls, int n) {
    __shared__ float As[32][64];
    __shared__ float Ws[32][128];  // cols 0..63 = Wmu, 64..127 = Wls
    int tid = threadIdx.x;
    int row0b = blockIdx.x * 64;
    int tx = tid & 31, ty = tid >> 5;
    int col0 = tx * 4, r0 = ty * 8;
    float4 acc[8];
#pragma unroll
    for (int i = 0; i < 8; ++i) acc[i] = make_float4(0.f, 0.f, 0.f, 0.f);

    int sr = tid & 63;
    int sq = (tid >> 6) * 4;
    int grow = row0b + sr;

    for (int kc = 0; kc < 128; kc += 32) {
#pragma unroll
        for (int j = 0; j < 2; ++j) {
            int qk = sq + j * 16;
            float4 v = make_float4(0.f, 0.f, 0.f, 0.f);
            if (grow < n) v = *(const float4*)(A + (size_t)grow * FEAT + kc + qk);
            As[qk + 0][sr] = v.x; As[qk + 1][sr] = v.y;
            As[qk + 2][sr] = v.z; As[qk + 3][sr] = v.w;
        }
#pragma unroll
        for (int j = 0; j < 4; ++j) {
            int idx = tid + j * 256;
            int wk = idx >> 5;
            int wc = (idx & 31) * 4;
            const float* Wp = (wc < 64) ? (Wmu + (size_t)(kc + wk) * 64 + wc)
                                        : (Wls + (size_t)(kc + wk) * 64 + (wc - 64));
            *(float4*)&Ws[wk][wc] = *(const float4*)Wp;
        }
        __syncthreads();
#pragma unroll
        for (int k = 0; k < 32; ++k) {
            float4 w = *(float4*)&Ws[k][col0];
            float a[8];
            *(float4*)&a[0] = *(float4*)&As[k][r0];
            *(float4*)&a[4] = *(float4*)&As[k][r0 + 4];
#pragma unroll
            for (int i = 0; i < 8; ++i) {
                acc[i].x += a[i] * w.x;
                acc[i].y += a[i] * w.y;
                acc[i].z += a[i] * w.z;
                acc[i].w += a[i] * w.w;
            }
        }
        __syncthreads();
    }
    bool is_mu = (col0 < 64);
    int c = is_mu ? col0 : col0 - 64;
    const float* bp = is_mu ? (bmu + c) : (bls + c);
    float4 b = *(const float4*)bp;
    float* op = is_mu ? mu : ls;
#pragma unroll
    for (int i = 0; i < 8; ++i) {
        int row = row0b + r0 + i;
        if (row < n)
            *(float4*)(op + (size_t)row * 64 + c) =
                make_float4(acc[i].x + b.x, acc[i].y + b.y, acc[i].z + b.z, acc[i].w + b.w);
    }
}

// ---------------- aggregation: out = [relu](A_norm @ t + bias) ----------------
// wave per node; lane holds float2 of the 128 features; 4-deep gather pipeline
__global__ __launch_bounds__(256) void k_agg(const float* __restrict__ t,
                                             const int* __restrict__ row_ptr,
                                             const int2* __restrict__ csr,
                                             const float* __restrict__ dis,
                                             const float* __restrict__ bias,
                                             float* __restrict__ out, int n, int do_relu) {
    int wave = (int)((blockIdx.x * blockDim.x + threadIdx.x) >> 6);
    int lane = threadIdx.x & 63;
    if (wave >= n) return;
    int node = wave;
    float d = dis[node];
    float sw = d * d;
    size_t lo = (size_t)(lane << 1);
    float2 self = *(const float2*)(t + (size_t)node * FEAT + lo);
    float2 a0, a1, a2, a3;
    a0.x = self.x * sw; a0.y = self.y * sw;
    a1.x = 0.f; a1.y = 0.f;
    a2.x = 0.f; a2.y = 0.f;
    a3.x = 0.f; a3.y = 0.f;
    int e = row_ptr[node], e1 = row_ptr[node + 1];
    for (; e + 4 <= e1; e += 4) {
        int2 c0 = csr[e + 0];
        int2 c1 = csr[e + 1];
        int2 c2 = csr[e + 2];
        int2 c3 = csr[e + 3];
        float2 v0 = *(const float2*)(t + (size_t)c0.x * FEAT + lo);
        float2 v1 = *(const float2*)(t + (size_t)c1.x * FEAT + lo);
        float2 v2 = *(const float2*)(t + (size_t)c2.x * FEAT + lo);
        float2 v3 = *(const float2*)(t + (size_t)c3.x * FEAT + lo);
        float w0 = __int_as_float(c0.y), w1 = __int_as_float(c1.y);
        float w2 = __int_as_float(c2.y), w3 = __int_as_float(c3.y);
        a0.x += w0 * v0.x; a0.y += w0 * v0.y;
        a1.x += w1 * v1.x; a1.y += w1 * v1.y;
        a2.x += w2 * v2.x; a2.y += w2 * v2.y;
        a3.x += w3 * v3.x; a3.y += w3 * v3.y;
    }
    for (; e < e1; ++e) {
        int2 c0 = csr[e];
        float w0 = __int_as_float(c0.y);
        float2 v0 = *(const float2*)(t + (size_t)c0.x * FEAT + lo);
        a0.x += w0 * v0.x; a0.y += w0 * v0.y;
    }
    a0.x += a1.x + a2.x + a3.x;
    a0.y += a1.y + a2.y + a3.y;
    if (bias) {
        a0.x += bias[lane << 1];
        a0.y += bias[(lane << 1) + 1];
    }
    if (do_relu) {
        a0.x = fmaxf(a0.x, 0.f);
        a0.y = fmaxf(a0.y, 0.f);
    }
    *(float2*)(out + (size_t)node * FEAT + lo) = a0;
}

extern "C" void kernel_launch(void* const* d_in, const int* in_sizes, int n_in,
                              void* d_out, int out_size, void* d_ws, size_t ws_size,
                              hipStream_t stream) {
    const float* x   = (const float*)d_in[0];
    const int*   ei  = (const int*)d_in[1];
    const float* W1  = (const float*)d_in[2];
    const float* b1  = (const float*)d_in[3];
    const float* W2  = (const float*)d_in[4];
    const float* b2  = (const float*)d_in[5];
    const float* W3  = (const float*)d_in[6];
    const float* b3  = (const float*)d_in[7];
    const float* Wmu = (const float*)d_in[8];
    const float* bmu = (const float*)d_in[9];
    const float* Wls = (const float*)d_in[10];
    const float* bls = (const float*)d_in[11];

    int n = in_sizes[0] / FEAT;    // 50000
    int E = in_sizes[1] / 2;       // 1,600,000

    char* ws = (char*)d_ws;
    size_t off = 0;
    auto alloc = [&](size_t bytes) {
        void* p = ws + off;
        off = (off + bytes + 255) & ~(size_t)255;
        return p;
    };
    float* Bt       = (float*)alloc((size_t)n * FEAT * 4);
    float* Bh       = (float*)alloc((size_t)n * FEAT * 4);
    int*   deg      = (int*)alloc((size_t)n * 4);
    float* dis      = (float*)alloc((size_t)n * 4);
    int*   row_ptr  = (int*)alloc((size_t)(n + 1) * 4);
    int*   cursor   = (int*)alloc((size_t)n * 4);
    int2*  csr      = (int2*)alloc((size_t)E * 8);

    hipMemsetAsync(deg, 0, (size_t)n * 4, stream);

    int eb = (E + 255) / 256;
    k_count_deg<<<eb, 256, 0, stream>>>(ei, E, deg);
    k_dis<<<(n + 255) / 256, 256, 0, stream>>>(deg, dis, n);
    k_scan<<<1, 1024, 0, stream>>>(deg, row_ptr, cursor, n);
    k_fill_csr<<<eb, 256, 0, stream>>>(ei, E, dis, cursor, csr);

    int gb = (n + 63) / 64;
    int ab = (n + 3) / 4;
    float* mu = (float*)d_out;
    float* ls = (float*)d_out + (size_t)n * 64;

    k_gemm128<<<gb, 256, 0, stream>>>(x,  W1, Bt, n);
    k_agg<<<ab, 256, 0, stream>>>(Bt, row_ptr, csr, dis, b1, Bh, n, 1);
    k_gemm128<<<gb, 256, 0, stream>>>(Bh, W2, Bt, n);
    k_agg<<<ab, 256, 0, stream>>>(Bt, row_ptr, csr, dis, b2, Bh, n, 1);
    k_gemm128<<<gb, 256, 0, stream>>>(Bh, W3, Bt, n);
    k_agg<<<ab, 256, 0, stream>>>(Bt, row_ptr, csr, dis, b3, Bh, n, 1);
    // g = A_norm @ h3 (shared by both heads; aggregation is linear)
    k_agg<<<ab, 256, 0, stream>>>(Bh, row_ptr, csr, dis, nullptr, Bt, n, 0);
    k_gemm_head<<<gb, 256, 0, stream>>>(Bt, Wmu, Wls, bmu, bls, mu, ls, n);
}

// Round 10
// 788.410 us; speedup vs baseline: 2.3970x; 1.1424x over previous
//
#include <hip/hip_runtime.h>

#define FEAT 128

// ---------------- degree histogram ----------------
__global__ void k_count_deg(const int* __restrict__ ei, int E, int* __restrict__ deg) {
    int e = blockIdx.x * blockDim.x + threadIdx.x;
    if (e < E) atomicAdd(&deg[ei[E + e]], 1);
}

__global__ void k_dis(const int* __restrict__ deg, float* __restrict__ dis, int n) {
    int i = blockIdx.x * blockDim.x + threadIdx.x;
    if (i < n) dis[i] = rsqrtf((float)(1 + deg[i]));
}

// ---------------- parallel 3-phase exclusive scan (512 elems / block) ----------------
__global__ __launch_bounds__(256) void k_scan1(const int* __restrict__ deg, int n,
                                               int* __restrict__ bsum) {
    int tid = threadIdx.x;
    int i0 = blockIdx.x * 512 + tid * 2;
    int v0 = (i0 < n) ? deg[i0] : 0;
    int v1 = (i0 + 1 < n) ? deg[i0 + 1] : 0;
    __shared__ int s[256];
    s[tid] = v0 + v1;
    __syncthreads();
    for (int off = 128; off > 0; off >>= 1) {
        if (tid < off) s[tid] += s[tid + off];
        __syncthreads();
    }
    if (tid == 0) bsum[blockIdx.x] = s[0];
}

__global__ __launch_bounds__(256) void k_scan2(int* __restrict__ bsum, int nb) {
    // single block; nb <= 256
    int tid = threadIdx.x;
    __shared__ int s[256];
    int v = (tid < nb) ? bsum[tid] : 0;
    s[tid] = v;
    __syncthreads();
    for (int off = 1; off < 256; off <<= 1) {
        int t = (tid >= off) ? s[tid - off] : 0;
        __syncthreads();
        s[tid] += t;
        __syncthreads();
    }
    if (tid < nb) bsum[tid] = s[tid] - v;   // exclusive
}

__global__ __launch_bounds__(256) void k_scan3(const int* __restrict__ deg, int n, int E,
                                               const int* __restrict__ bsum,
                                               int* __restrict__ row_ptr,
                                               int* __restrict__ cursor) {
    int tid = threadIdx.x;
    int i0 = blockIdx.x * 512 + tid * 2;
    int v0 = (i0 < n) ? deg[i0] : 0;
    int v1 = (i0 + 1 < n) ? deg[i0 + 1] : 0;
    __shared__ int s[256];
    int pair = v0 + v1;
    s[tid] = pair;
    __syncthreads();
    for (int off = 1; off < 256; off <<= 1) {
        int t = (tid >= off) ? s[tid - off] : 0;
        __syncthreads();
        s[tid] += t;
        __syncthreads();
    }
    int excl = s[tid] - pair + bsum[blockIdx.x];
    if (i0 < n)     { row_ptr[i0] = excl;          cursor[i0] = excl; }
    if (i0 + 1 < n) { row_ptr[i0 + 1] = excl + v0; cursor[i0 + 1] = excl + v0; }
    if (blockIdx.x == 0 && tid == 0) row_ptr[n] = E;
}

// ---------------- CSR fill: ONE 8B scatter per edge (src + norm packed) ----------------
__global__ void k_fill_csr(const int* __restrict__ ei, int E,
                           const float* __restrict__ dis,
                           int* __restrict__ cursor,
                           int2* __restrict__ csr) {
    int e = blockIdx.x * blockDim.x + threadIdx.x;
    if (e >= E) return;
    int s = ei[e], d = ei[E + e];
    int pos = atomicAdd(&cursor[d], 1);
    csr[pos] = make_int2(s, __float_as_int(dis[s] * dis[d]));
}

// ---------------- GEMM: out[n,128] = A[n,128] @ W[128,128], 64x128 tile, 8x4/thread ----------------
__global__ __launch_bounds__(256) void k_gemm128(const float* __restrict__ A,
                                                 const float* __restrict__ W,
                                                 float* __restrict__ out, int n) {
    __shared__ float As[32][64];    // As[k][row]; bank = row%32 -> 2-way on store (free)
    __shared__ float Ws[32][128];
    int tid = threadIdx.x;
    int row0b = blockIdx.x * 64;
    int tx = tid & 31, ty = tid >> 5;
    int col0 = tx * 4, r0 = ty * 8;
    float4 acc[8];
#pragma unroll
    for (int i = 0; i < 8; ++i) acc[i] = make_float4(0.f, 0.f, 0.f, 0.f);

    int sr = tid & 63;
    int sq = (tid >> 6) * 4;
    int grow = row0b + sr;

    for (int kc = 0; kc < 128; kc += 32) {
#pragma unroll
        for (int j = 0; j < 2; ++j) {
            int qk = sq + j * 16;
            float4 v = make_float4(0.f, 0.f, 0.f, 0.f);
            if (grow < n) v = *(const float4*)(A + (size_t)grow * FEAT + kc + qk);
            As[qk + 0][sr] = v.x; As[qk + 1][sr] = v.y;
            As[qk + 2][sr] = v.z; As[qk + 3][sr] = v.w;
        }
#pragma unroll
        for (int j = 0; j < 4; ++j) {
            int idx = tid + j * 256;       // 1024 float4 slots
            int wk = idx >> 5;
            int wc = (idx & 31) * 4;
            *(float4*)&Ws[wk][wc] = *(const float4*)(W + (size_t)(kc + wk) * 128 + wc);
        }
        __syncthreads();
#pragma unroll
        for (int k = 0; k < 32; ++k) {
            float4 w = *(float4*)&Ws[k][col0];
            float a[8];
            *(float4*)&a[0] = *(float4*)&As[k][r0];
            *(float4*)&a[4] = *(float4*)&As[k][r0 + 4];
#pragma unroll
            for (int i = 0; i < 8; ++i) {
                acc[i].x += a[i] * w.x;
                acc[i].y += a[i] * w.y;
                acc[i].z += a[i] * w.z;
                acc[i].w += a[i] * w.w;
            }
        }
        __syncthreads();
    }
#pragma unroll
    for (int i = 0; i < 8; ++i) {
        int row = row0b + r0 + i;
        if (row < n)
            *(float4*)(out + (size_t)row * 128 + col0) = acc[i];
    }
}

// ---------------- head GEMM: [mu|ls] = A @ [Wmu|Wls] + [bmu|bls] ----------------
__global__ __launch_bounds__(256) void k_gemm_head(const float* __restrict__ A,
                                                   const float* __restrict__ Wmu,
                                                   const float* __restrict__ Wls,
                                                   const float* __restrict__ bmu,
                                                   const float* __restrict__ bls,
                                                   float* __restrict__ mu,
                                                   float* __restrict__ ls, int n) {
    __shared__ float As[32][64];
    __shared__ float Ws[32][128];  // cols 0..63 = Wmu, 64..127 = Wls
    int tid = threadIdx.x;
    int row0b = blockIdx.x * 64;
    int tx = tid & 31, ty = tid >> 5;
    int col0 = tx * 4, r0 = ty * 8;
    float4 acc[8];
#pragma unroll
    for (int i = 0; i < 8; ++i) acc[i] = make_float4(0.f, 0.f, 0.f, 0.f);

    int sr = tid & 63;
    int sq = (tid >> 6) * 4;
    int grow = row0b + sr;

    for (int kc = 0; kc < 128; kc += 32) {
#pragma unroll
        for (int j = 0; j < 2; ++j) {
            int qk = sq + j * 16;
            float4 v = make_float4(0.f, 0.f, 0.f, 0.f);
            if (grow < n) v = *(const float4*)(A + (size_t)grow * FEAT + kc + qk);
            As[qk + 0][sr] = v.x; As[qk + 1][sr] = v.y;
            As[qk + 2][sr] = v.z; As[qk + 3][sr] = v.w;
        }
#pragma unroll
        for (int j = 0; j < 4; ++j) {
            int idx = tid + j * 256;
            int wk = idx >> 5;
            int wc = (idx & 31) * 4;
            const float* Wp = (wc < 64) ? (Wmu + (size_t)(kc + wk) * 64 + wc)
                                        : (Wls + (size_t)(kc + wk) * 64 + (wc - 64));
            *(float4*)&Ws[wk][wc] = *(const float4*)Wp;
        }
        __syncthreads();
#pragma unroll
        for (int k = 0; k < 32; ++k) {
            float4 w = *(float4*)&Ws[k][col0];
            float a[8];
            *(float4*)&a[0] = *(float4*)&As[k][r0];
            *(float4*)&a[4] = *(float4*)&As[k][r0 + 4];
#pragma unroll
            for (int i = 0; i < 8; ++i) {
                acc[i].x += a[i] * w.x;
                acc[i].y += a[i] * w.y;
                acc[i].z += a[i] * w.z;
                acc[i].w += a[i] * w.w;
            }
        }
        __syncthreads();
    }
    bool is_mu = (col0 < 64);
    int c = is_mu ? col0 : col0 - 64;
    const float* bp = is_mu ? (bmu + c) : (bls + c);
    float4 b = *(const float4*)bp;
    float* op = is_mu ? mu : ls;
#pragma unroll
    for (int i = 0; i < 8; ++i) {
        int row = row0b + r0 + i;
        if (row < n)
            *(float4*)(op + (size_t)row * 64 + c) =
                make_float4(acc[i].x + b.x, acc[i].y + b.y, acc[i].z + b.z, acc[i].w + b.w);
    }
}

// ---------------- aggregation: out = [relu](A_norm @ t + bias) ----------------
// wave per node; lane holds float2 of the 128 features; 8-deep gather pipeline
__global__ __launch_bounds__(256) void k_agg(const float* __restrict__ t,
                                             const int* __restrict__ row_ptr,
                                             const int2* __restrict__ csr,
                                             const float* __restrict__ dis,
                                             const float* __restrict__ bias,
                                             float* __restrict__ out, int n, int do_relu) {
    int wave = (int)((blockIdx.x * blockDim.x + threadIdx.x) >> 6);
    int lane = threadIdx.x & 63;
    if (wave >= n) return;
    int node = wave;
    float d = dis[node];
    float sw = d * d;
    size_t lo = (size_t)(lane << 1);
    float2 self = *(const float2*)(t + (size_t)node * FEAT + lo);
    float2 acc[8];
    acc[0].x = self.x * sw; acc[0].y = self.y * sw;
#pragma unroll
    for (int i = 1; i < 8; ++i) { acc[i].x = 0.f; acc[i].y = 0.f; }
    int e = row_ptr[node], e1 = row_ptr[node + 1];
    for (; e + 8 <= e1; e += 8) {
        int2 c[8];
#pragma unroll
        for (int i = 0; i < 8; ++i) c[i] = csr[e + i];
        float2 v[8];
#pragma unroll
        for (int i = 0; i < 8; ++i)
            v[i] = *(const float2*)(t + (size_t)c[i].x * FEAT + lo);
#pragma unroll
        for (int i = 0; i < 8; ++i) {
            float w = __int_as_float(c[i].y);
            acc[i].x += w * v[i].x;
            acc[i].y += w * v[i].y;
        }
    }
    for (; e + 4 <= e1; e += 4) {
        int2 c[4];
#pragma unroll
        for (int i = 0; i < 4; ++i) c[i] = csr[e + i];
#pragma unroll
        for (int i = 0; i < 4; ++i) {
            float w = __int_as_float(c[i].y);
            float2 v = *(const float2*)(t + (size_t)c[i].x * FEAT + lo);
            acc[i].x += w * v.x;
            acc[i].y += w * v.y;
        }
    }
    for (; e < e1; ++e) {
        int2 c0 = csr[e];
        float w0 = __int_as_float(c0.y);
        float2 v0 = *(const float2*)(t + (size_t)c0.x * FEAT + lo);
        acc[0].x += w0 * v0.x; acc[0].y += w0 * v0.y;
    }
#pragma unroll
    for (int i = 1; i < 8; ++i) { acc[0].x += acc[i].x; acc[0].y += acc[i].y; }
    if (bias) {
        acc[0].x += bias[lane << 1];
        acc[0].y += bias[(lane << 1) + 1];
    }
    if (do_relu) {
        acc[0].x = fmaxf(acc[0].x, 0.f);
        acc[0].y = fmaxf(acc[0].y, 0.f);
    }
    *(float2*)(out + (size_t)node * FEAT + lo) = acc[0];
}

extern "C" void kernel_launch(void* const* d_in, const int* in_sizes, int n_in,
                              void* d_out, int out_size, void* d_ws, size_t ws_size,
                              hipStream_t stream) {
    const float* x   = (const float*)d_in[0];
    const int*   ei  = (const int*)d_in[1];
    const float* W1  = (const float*)d_in[2];
    const float* b1  = (const float*)d_in[3];
    const float* W2  = (const float*)d_in[4];
    const float* b2  = (const float*)d_in[5];
    const float* W3  = (const float*)d_in[6];
    const float* b3  = (const float*)d_in[7];
    const float* Wmu = (const float*)d_in[8];
    const float* bmu = (const float*)d_in[9];
    const float* Wls = (const float*)d_in[10];
    const float* bls = (const float*)d_in[11];

    int n = in_sizes[0] / FEAT;    // 50000
    int E = in_sizes[1] / 2;       // 1,600,000

    char* ws = (char*)d_ws;
    size_t off = 0;
    auto alloc = [&](size_t bytes) {
        void* p = ws + off;
        off = (off + bytes + 255) & ~(size_t)255;
        return p;
    };
    float* Bt       = (float*)alloc((size_t)n * FEAT * 4);
    float* Bh       = (float*)alloc((size_t)n * FEAT * 4);
    int*   deg      = (int*)alloc((size_t)n * 4);
    float* dis      = (float*)alloc((size_t)n * 4);
    int*   row_ptr  = (int*)alloc((size_t)(n + 1) * 4);
    int*   cursor   = (int*)alloc((size_t)n * 4);
    int*   bsum     = (int*)alloc(256 * 4);
    int2*  csr      = (int2*)alloc((size_t)E * 8);

    hipMemsetAsync(deg, 0, (size_t)n * 4, stream);

    int eb = (E + 255) / 256;
    int nb = (n + 511) / 512;      // 98 scan blocks
    k_count_deg<<<eb, 256, 0, stream>>>(ei, E, deg);
    k_dis<<<(n + 255) / 256, 256, 0, stream>>>(deg, dis, n);
    k_scan1<<<nb, 256, 0, stream>>>(deg, n, bsum);
    k_scan2<<<1, 256, 0, stream>>>(bsum, nb);
    k_scan3<<<nb, 256, 0, stream>>>(deg, n, E, bsum, row_ptr, cursor);
    k_fill_csr<<<eb, 256, 0, stream>>>(ei, E, dis, cursor, csr);

    int gb = (n + 63) / 64;
    int ab = (n + 3) / 4;
    float* mu = (float*)d_out;
    float* ls = (float*)d_out + (size_t)n * 64;

    k_gemm128<<<gb, 256, 0, stream>>>(x,  W1, Bt, n);
    k_agg<<<ab, 256, 0, stream>>>(Bt, row_ptr, csr, dis, b1, Bh, n, 1);
    k_gemm128<<<gb, 256, 0, stream>>>(Bh, W2, Bt, n);
    k_agg<<<ab, 256, 0, stream>>>(Bt, row_ptr, csr, dis, b2, Bh, n, 1);
    k_gemm128<<<gb, 256, 0, stream>>>(Bh, W3, Bt, n);
    k_agg<<<ab, 256, 0, stream>>>(Bt, row_ptr, csr, dis, b3, Bh, n, 1);
    // g = A_norm @ h3 (shared by both heads; aggregation is linear)
    k_agg<<<ab, 256, 0, stream>>>(Bh, row_ptr, csr, dis, nullptr, Bt, n, 0);
    k_gemm_head<<<gb, 256, 0, stream>>>(Bt, Wmu, Wls, bmu, bls, mu, ls, n);
}

// Round 15
// 614.731 us; speedup vs baseline: 3.0742x; 1.2825x over previous
//
#include <hip/hip_runtime.h>
#include <hip/hip_fp16.h>

#define FEAT 128

struct half4 { __half2 lo, hi; };

// ---------------- degree histogram ----------------
__global__ void k_count_deg(const int* __restrict__ ei, int E, int* __restrict__ deg) {
    int e = blockIdx.x * blockDim.x + threadIdx.x;
    if (e < E) atomicAdd(&deg[ei[E + e]], 1);
}

__global__ void k_dis(const int* __restrict__ deg, float* __restrict__ dis, int n) {
    int i = blockIdx.x * blockDim.x + threadIdx.x;
    if (i < n) dis[i] = rsqrtf((float)(1 + deg[i]));
}

// ---------------- parallel 3-phase exclusive scan (512 elems / block) ----------------
__global__ __launch_bounds__(256) void k_scan1(const int* __restrict__ deg, int n,
                                               int* __restrict__ bsum) {
    int tid = threadIdx.x;
    int i0 = blockIdx.x * 512 + tid * 2;
    int v0 = (i0 < n) ? deg[i0] : 0;
    int v1 = (i0 + 1 < n) ? deg[i0 + 1] : 0;
    __shared__ int s[256];
    s[tid] = v0 + v1;
    __syncthreads();
    for (int off = 128; off > 0; off >>= 1) {
        if (tid < off) s[tid] += s[tid + off];
        __syncthreads();
    }
    if (tid == 0) bsum[blockIdx.x] = s[0];
}

__global__ __launch_bounds__(256) void k_scan2(int* __restrict__ bsum, int nb) {
    // single block; nb <= 256
    int tid = threadIdx.x;
    __shared__ int s[256];
    int v = (tid < nb) ? bsum[tid] : 0;
    s[tid] = v;
    __syncthreads();
    for (int off = 1; off < 256; off <<= 1) {
        int t = (tid >= off) ? s[tid - off] : 0;
        __syncthreads();
        s[tid] += t;
        __syncthreads();
    }
    if (tid < nb) bsum[tid] = s[tid] - v;   // exclusive
}

__global__ __launch_bounds__(256) void k_scan3(const int* __restrict__ deg, int n, int E,
                                               const int* __restrict__ bsum,
                                               int* __restrict__ row_ptr,
                                               int* __restrict__ cursor) {
    int tid = threadIdx.x;
    int i0 = blockIdx.x * 512 + tid * 2;
    int v0 = (i0 < n) ? deg[i0] : 0;
    int v1 = (i0 + 1 < n) ? deg[i0 + 1] : 0;
    __shared__ int s[256];
    int pair = v0 + v1;
    s[tid] = pair;
    __syncthreads();
    for (int off = 1; off < 256; off <<= 1) {
        int t = (tid >= off) ? s[tid - off] : 0;
        __syncthreads();
        s[tid] += t;
        __syncthreads();
    }
    int excl = s[tid] - pair + bsum[blockIdx.x];
    if (i0 < n)     { row_ptr[i0] = excl;          cursor[i0] = excl; }
    if (i0 + 1 < n) { row_ptr[i0 + 1] = excl + v0; cursor[i0 + 1] = excl + v0; }
    if (blockIdx.x == 0 && tid == 0) row_ptr[n] = E;
}

// ---------------- CSR fill: ONE 8B scatter per edge (src + norm packed) ----------------
__global__ void k_fill_csr(const int* __restrict__ ei, int E,
                           const float* __restrict__ dis,
                           int* __restrict__ cursor,
                           int2* __restrict__ csr) {
    int e = blockIdx.x * blockDim.x + threadIdx.x;
    if (e >= E) return;
    int s = ei[e], d = ei[E + e];
    int pos = atomicAdd(&cursor[d], 1);
    csr[pos] = make_int2(s, __float_as_int(dis[s] * dis[d]));
}

// ---------------- GEMM: out[n,128] = A[n,128] @ W[128,128]; dual-store f32 + f16 ----------------
__global__ __launch_bounds__(256) void k_gemm128(const float* __restrict__ A,
                                                 const float* __restrict__ W,
                                                 float* __restrict__ out,
                                                 __half* __restrict__ out16, int n) {
    __shared__ float As[32][64];    // As[k][row]; bank = row%32 -> 2-way on store (free)
    __shared__ float Ws[32][128];
    int tid = threadIdx.x;
    int row0b = blockIdx.x * 64;
    int tx = tid & 31, ty = tid >> 5;
    int col0 = tx * 4, r0 = ty * 8;
    float4 acc[8];
#pragma unroll
    for (int i = 0; i < 8; ++i) acc[i] = make_float4(0.f, 0.f, 0.f, 0.f);

    int sr = tid & 63;
    int sq = (tid >> 6) * 4;
    int grow = row0b + sr;

    for (int kc = 0; kc < 128; kc += 32) {
#pragma unroll
        for (int j = 0; j < 2; ++j) {
            int qk = sq + j * 16;
            float4 v = make_float4(0.f, 0.f, 0.f, 0.f);
            if (grow < n) v = *(const float4*)(A + (size_t)grow * FEAT + kc + qk);
            As[qk + 0][sr] = v.x; As[qk + 1][sr] = v.y;
            As[qk + 2][sr] = v.z; As[qk + 3][sr] = v.w;
        }
#pragma unroll
        for (int j = 0; j < 4; ++j) {
            int idx = tid + j * 256;       // 1024 float4 slots
            int wk = idx >> 5;
            int wc = (idx & 31) * 4;
            *(float4*)&Ws[wk][wc] = *(const float4*)(W + (size_t)(kc + wk) * 128 + wc);
        }
        __syncthreads();
#pragma unroll
        for (int k = 0; k < 32; ++k) {
            float4 w = *(float4*)&Ws[k][col0];
            float a[8];
            *(float4*)&a[0] = *(float4*)&As[k][r0];
            *(float4*)&a[4] = *(float4*)&As[k][r0 + 4];
#pragma unroll
            for (int i = 0; i < 8; ++i) {
                acc[i].x += a[i] * w.x;
                acc[i].y += a[i] * w.y;
                acc[i].z += a[i] * w.z;
                acc[i].w += a[i] * w.w;
            }
        }
        __syncthreads();
    }
#pragma unroll
    for (int i = 0; i < 8; ++i) {
        int row = row0b + r0 + i;
        if (row < n) {
            *(float4*)(out + (size_t)row * 128 + col0) = acc[i];
            half4 h;
            h.lo = __floats2half2_rn(acc[i].x, acc[i].y);
            h.hi = __floats2half2_rn(acc[i].z, acc[i].w);
            *(half4*)(out16 + (size_t)row * 128 + col0) = h;
        }
    }
}

// ---------------- head GEMM: [mu|ls] = A @ [Wmu|Wls] + [bmu|bls] ----------------
__global__ __launch_bounds__(256) void k_gemm_head(const float* __restrict__ A,
                                                   const float* __restrict__ Wmu,
                                                   const float* __restrict__ Wls,
                                                   const float* __restrict__ bmu,
                                                   const float* __restrict__ bls,
                                                   float* __restrict__ mu,
                                                   float* __restrict__ ls, int n) {
    __shared__ float As[32][64];
    __shared__ float Ws[32][128];  // cols 0..63 = Wmu, 64..127 = Wls
    int tid = threadIdx.x;
    int row0b = blockIdx.x * 64;
    int tx = tid & 31, ty = tid >> 5;
    int col0 = tx * 4, r0 = ty * 8;
    float4 acc[8];
#pragma unroll
    for (int i = 0; i < 8; ++i) acc[i] = make_float4(0.f, 0.f, 0.f, 0.f);

    int sr = tid & 63;
    int sq = (tid >> 6) * 4;
    int grow = row0b + sr;

    for (int kc = 0; kc < 128; kc += 32) {
#pragma unroll
        for (int j = 0; j < 2; ++j) {
            int qk = sq + j * 16;
            float4 v = make_float4(0.f, 0.f, 0.f, 0.f);
            if (grow < n) v = *(const float4*)(A + (size_t)grow * FEAT + kc + qk);
            As[qk + 0][sr] = v.x; As[qk + 1][sr] = v.y;
            As[qk + 2][sr] = v.z; As[qk + 3][sr] = v.w;
        }
#pragma unroll
        for (int j = 0; j < 4; ++j) {
            int idx = tid + j * 256;
            int wk = idx >> 5;
            int wc = (idx & 31) * 4;
            const float* Wp = (wc < 64) ? (Wmu + (size_t)(kc + wk) * 64 + wc)
                                        : (Wls + (size_t)(kc + wk) * 64 + (wc - 64));
            *(float4*)&Ws[wk][wc] = *(const float4*)Wp;
        }
        __syncthreads();
#pragma unroll
        for (int k = 0; k < 32; ++k) {
            float4 w = *(float4*)&Ws[k][col0];
            float a[8];
            *(float4*)&a[0] = *(float4*)&As[k][r0];
            *(float4*)&a[4] = *(float4*)&As[k][r0 + 4];
#pragma unroll
            for (int i = 0; i < 8; ++i) {
                acc[i].x += a[i] * w.x;
                acc[i].y += a[i] * w.y;
                acc[i].z += a[i] * w.z;
                acc[i].w += a[i] * w.w;
            }
        }
        __syncthreads();
    }
    bool is_mu = (col0 < 64);
    int c = is_mu ? col0 : col0 - 64;
    const float* bp = is_mu ? (bmu + c) : (bls + c);
    float4 b = *(const float4*)bp;
    float* op = is_mu ? mu : ls;
#pragma unroll
    for (int i = 0; i < 8; ++i) {
        int row = row0b + r0 + i;
        if (row < n)
            *(float4*)(op + (size_t)row * 64 + c) =
                make_float4(acc[i].x + b.x, acc[i].y + b.y, acc[i].z + b.z, acc[i].w + b.w);
    }
}

// ---------------- aggregation: out = [relu](A_norm @ t + bias) ----------------
// wave per node; lane holds 2 features; gathers from fp16 shadow table (4B/lane,
// 256B/row = full-line granularity); self-term + accum + output in f32.
// Optionally dual-stores an fp16 copy of the output (for the next gather pass).
__global__ __launch_bounds__(256) void k_agg(const float* __restrict__ t32,
                                             const __half* __restrict__ t16,
                                             const int* __restrict__ row_ptr,
                                             const int2* __restrict__ csr,
                                             const float* __restrict__ dis,
                                             const float* __restrict__ bias,
                                             float* __restrict__ out,
                                             __half* __restrict__ out16,
                                             int n, int do_relu) {
    int wave = (int)((blockIdx.x * blockDim.x + threadIdx.x) >> 6);
    int lane = threadIdx.x & 63;
    if (wave >= n) return;
    int node = wave;
    float d = dis[node];
    float sw = d * d;
    size_t lo = (size_t)(lane << 1);
    float2 self = *(const float2*)(t32 + (size_t)node * FEAT + lo);
    float2 acc[8];
    acc[0].x = self.x * sw; acc[0].y = self.y * sw;
#pragma unroll
    for (int i = 1; i < 8; ++i) { acc[i].x = 0.f; acc[i].y = 0.f; }
    int e = row_ptr[node], e1 = row_ptr[node + 1];
    for (; e + 8 <= e1; e += 8) {
        int2 c[8];
#pragma unroll
        for (int i = 0; i < 8; ++i) c[i] = csr[e + i];
        __half2 hv[8];
#pragma unroll
        for (int i = 0; i < 8; ++i)
            hv[i] = *((const __half2*)(t16 + ((size_t)c[i].x << 7)) + lane);
#pragma unroll
        for (int i = 0; i < 8; ++i) {
            float w = __int_as_float(c[i].y);
            float2 v = __half22float2(hv[i]);
            acc[i].x += w * v.x;
            acc[i].y += w * v.y;
        }
    }
    for (; e + 4 <= e1; e += 4) {
        int2 c[4];
#pragma unroll
        for (int i = 0; i < 4; ++i) c[i] = csr[e + i];
#pragma unroll
        for (int i = 0; i < 4; ++i) {
            float w = __int_as_float(c[i].y);
            float2 v = __half22float2(*((const __half2*)(t16 + ((size_t)c[i].x << 7)) + lane));
            acc[i].x += w * v.x;
            acc[i].y += w * v.y;
        }
    }
    for (; e < e1; ++e) {
        int2 c0 = csr[e];
        float w0 = __int_as_float(c0.y);
        float2 v0 = __half22float2(*((const __half2*)(t16 + ((size_t)c0.x << 7)) + lane));
        acc[0].x += w0 * v0.x; acc[0].y += w0 * v0.y;
    }
#pragma unroll
    for (int i = 1; i < 8; ++i) { acc[0].x += acc[i].x; acc[0].y += acc[i].y; }
    if (bias) {
        acc[0].x += bias[lane << 1];
        acc[0].y += bias[(lane << 1) + 1];
    }
    if (do_relu) {
        acc[0].x = fmaxf(acc[0].x, 0.f);
        acc[0].y = fmaxf(acc[0].y, 0.f);
    }
    *(float2*)(out + (size_t)node * FEAT + lo) = acc[0];
    if (out16)
        *((__half2*)(out16 + (size_t)node * FEAT) + lane) = __floats2half2_rn(acc[0].x, acc[0].y);
}

extern "C" void kernel_launch(void* const* d_in, const int* in_sizes, int n_in,
                              void* d_out, int out_size, void* d_ws, size_t ws_size,
                              hipStream_t stream) {
    const float* x   = (const float*)d_in[0];
    const int*   ei  = (const int*)d_in[1];
    const float* W1  = (const float*)d_in[2];
    const float* b1  = (const float*)d_in[3];
    const float* W2  = (const float*)d_in[4];
    const float* b2  = (const float*)d_in[5];
    const float* W3  = (const float*)d_in[6];
    const float* b3  = (const float*)d_in[7];
    const float* Wmu = (const float*)d_in[8];
    const float* bmu = (const float*)d_in[9];
    const float* Wls = (const float*)d_in[10];
    const float* bls = (const float*)d_in[11];

    int n = in_sizes[0] / FEAT;    // 50000
    int E = in_sizes[1] / 2;       // 1,600,000

    char* ws = (char*)d_ws;
    size_t off = 0;
    auto alloc = [&](size_t bytes) {
        void* p = ws + off;
        off = (off + bytes + 255) & ~(size_t)255;
        return p;
    };
    float*  Bt      = (float*)alloc((size_t)n * FEAT * 4);
    float*  Bh      = (float*)alloc((size_t)n * FEAT * 4);
    __half* Bt16    = (__half*)alloc((size_t)n * FEAT * 2);
    __half* Bh16    = (__half*)alloc((size_t)n * FEAT * 2);
    int*    deg     = (int*)alloc((size_t)n * 4);
    float*  dis     = (float*)alloc((size_t)n * 4);
    int*    row_ptr = (int*)alloc((size_t)(n + 1) * 4);
    int*    cursor  = (int*)alloc((size_t)n * 4);
    int*    bsum    = (int*)alloc(256 * 4);
    int2*   csr     = (int2*)alloc((size_t)E * 8);

    hipMemsetAsync(deg, 0, (size_t)n * 4, stream);

    int eb = (E + 255) / 256;
    int nb = (n + 511) / 512;      // 98 scan blocks
    k_count_deg<<<eb, 256, 0, stream>>>(ei, E, deg);
    k_dis<<<(n + 255) / 256, 256, 0, stream>>>(deg, dis, n);
    k_scan1<<<nb, 256, 0, stream>>>(deg, n, bsum);
    k_scan2<<<1, 256, 0, stream>>>(bsum, nb);
    k_scan3<<<nb, 256, 0, stream>>>(deg, n, E, bsum, row_ptr, cursor);
    k_fill_csr<<<eb, 256, 0, stream>>>(ei, E, dis, cursor, csr);

    int gb = (n + 63) / 64;
    int ab = (n + 3) / 4;
    float* mu = (float*)d_out;
    float* ls = (float*)d_out + (size_t)n * 64;

    k_gemm128<<<gb, 256, 0, stream>>>(x,  W1, Bt, Bt16, n);
    k_agg<<<ab, 256, 0, stream>>>(Bt, Bt16, row_ptr, csr, dis, b1, Bh, nullptr, n, 1);
    k_gemm128<<<gb, 256, 0, stream>>>(Bh, W2, Bt, Bt16, n);
    k_agg<<<ab, 256, 0, stream>>>(Bt, Bt16, row_ptr, csr, dis, b2, Bh, nullptr, n, 1);
    k_gemm128<<<gb, 256, 0, stream>>>(Bh, W3, Bt, Bt16, n);
    // h3: dual-store so the shared final aggregation can gather fp16
    k_agg<<<ab, 256, 0, stream>>>(Bt, Bt16, row_ptr, csr, dis, b3, Bh, Bh16, n, 1);
    // g = A_norm @ h3 (shared by both heads; aggregation is linear)
    k_agg<<<ab, 256, 0, stream>>>(Bh, Bh16, row_ptr, csr, dis, nullptr, Bt, nullptr, n, 0);
    k_gemm_head<<<gb, 256, 0, stream>>>(Bt, Wmu, Wls, bmu, bls, mu, ls, n);
}

// Round 16
// 507.781 us; speedup vs baseline: 3.7217x; 1.2106x over previous
//
#include <hip/hip_runtime.h>
#include <hip/hip_fp16.h>

#define FEAT 128
#define BKT_SHIFT 8
#define CHUNK 4096

struct half4 { __half2 lo, hi; };

// ---------------- phase A: per-block bucket histogram (bucket = dst>>8) ----------------
__global__ __launch_bounds__(256) void k_bhist(const int* __restrict__ dstp, int E, int BL,
                                               int* __restrict__ gh) {
    __shared__ int h[256];
    int tid = threadIdx.x, b = blockIdx.x;
    h[tid] = 0;
    __syncthreads();
    int cb = b * CHUNK;
    for (int i = tid; i < CHUNK; i += 256) {
        int e = cb + i;
        if (e < E) atomicAdd(&h[dstp[e] >> BKT_SHIFT], 1);
    }
    __syncthreads();
    gh[tid * BL + b] = h[tid];   // bucket-major
}

// ---------------- generic 3-phase exclusive scan (512 elems / block) ----------------
__global__ __launch_bounds__(256) void k_s1(const int* __restrict__ g, int len,
                                            int* __restrict__ bsum) {
    int tid = threadIdx.x;
    int i0 = blockIdx.x * 512 + tid * 2;
    int v0 = (i0 < len) ? g[i0] : 0;
    int v1 = (i0 + 1 < len) ? g[i0 + 1] : 0;
    __shared__ int s[256];
    s[tid] = v0 + v1;
    __syncthreads();
    for (int off = 128; off > 0; off >>= 1) {
        if (tid < off) s[tid] += s[tid + off];
        __syncthreads();
    }
    if (tid == 0) bsum[blockIdx.x] = s[0];
}

__global__ __launch_bounds__(256) void k_s2(int* __restrict__ bsum, int nb) {
    int tid = threadIdx.x;
    __shared__ int s[256];
    int v = (tid < nb) ? bsum[tid] : 0;
    s[tid] = v;
    __syncthreads();
    for (int off = 1; off < 256; off <<= 1) {
        int t = (tid >= off) ? s[tid - off] : 0;
        __syncthreads();
        s[tid] += t;
        __syncthreads();
    }
    if (tid < nb) bsum[tid] = s[tid] - v;   // exclusive
}

__global__ __launch_bounds__(256) void k_s3(const int* __restrict__ g, int len,
                                            const int* __restrict__ bsum,
                                            int* __restrict__ out) {
    int tid = threadIdx.x;
    int i0 = blockIdx.x * 512 + tid * 2;
    int v0 = (i0 < len) ? g[i0] : 0;
    int v1 = (i0 + 1 < len) ? g[i0 + 1] : 0;
    __shared__ int s[256];
    int pair = v0 + v1;
    s[tid] = pair;
    __syncthreads();
    for (int off = 1; off < 256; off <<= 1) {
        int t = (tid >= off) ? s[tid - off] : 0;
        __syncthreads();
        s[tid] += t;
        __syncthreads();
    }
    int excl = s[tid] - pair + bsum[blockIdx.x];
    if (i0 < len)     out[i0] = excl;
    if (i0 + 1 < len) out[i0 + 1] = excl + v0;
}

// ---------------- phase C: scatter edges into bucket-sorted ebuf ----------------
__global__ __launch_bounds__(256) void k_bscatter(const int* __restrict__ ei, int E, int BL,
                                                  const int* __restrict__ gscan,
                                                  int2* __restrict__ ebuf) {
    __shared__ int lcur[256];
    int tid = threadIdx.x, b = blockIdx.x;
    lcur[tid] = gscan[tid * BL + b];
    __syncthreads();
    int cb = b * CHUNK;
    for (int i = tid; i < CHUNK; i += 256) {
        int e = cb + i;
        if (e < E) {
            int s = ei[e], d = ei[E + e];
            int pos = atomicAdd(&lcur[d >> BKT_SHIFT], 1);
            ebuf[pos] = make_int2(s, d);
        }
    }
}

// ---------------- phase D1: per-bucket deg count -> row_ptr + dis ----------------
__global__ __launch_bounds__(256) void k_bdeg(const int2* __restrict__ ebuf,
                                              const int* __restrict__ gscan, int BL,
                                              int n, int E,
                                              int* __restrict__ row_ptr,
                                              float* __restrict__ dis) {
    __shared__ int sdeg[256], soff[256];
    int tid = threadIdx.x, k = blockIdx.x;
    int base = k << BKT_SHIFT;
    int start = gscan[k * BL];
    int end = gscan[(k + 1) * BL];   // gh allocated for 256 buckets; k+1 <= NBK <= 255
    sdeg[tid] = 0;
    __syncthreads();
    for (int e = start + tid; e < end; e += 256)
        atomicAdd(&sdeg[ebuf[e].y - base], 1);
    __syncthreads();
    int v = sdeg[tid];
    soff[tid] = v;
    __syncthreads();
    for (int off = 1; off < 256; off <<= 1) {
        int t = (tid >= off) ? soff[tid - off] : 0;
        __syncthreads();
        soff[tid] += t;
        __syncthreads();
    }
    int node = base + tid;
    if (node < n) {
        row_ptr[node] = start + soff[tid] - v;
        dis[node] = rsqrtf((float)(1 + v));
    }
    if (k == 0 && tid == 0) row_ptr[n] = E;
}

// ---------------- phase D2: per-bucket CSR fill (LDS cursors, windowed writes) ----------------
__global__ __launch_bounds__(256) void k_bfill(const int2* __restrict__ ebuf,
                                               const int* __restrict__ gscan, int BL,
                                               int n, int E,
                                               const int* __restrict__ row_ptr,
                                               const float* __restrict__ dis,
                                               int2* __restrict__ csr) {
    __shared__ int scur[256];
    int tid = threadIdx.x, k = blockIdx.x;
    int base = k << BKT_SHIFT;
    int start = gscan[k * BL];
    int end = gscan[(k + 1) * BL];
    int node = base + tid;
    scur[tid] = (node < n) ? row_ptr[node] : 0;
    __syncthreads();
    for (int e = start + tid; e < end; e += 256) {
        int2 ed = ebuf[e];
        int pos = atomicAdd(&scur[ed.y - base], 1);
        csr[pos] = make_int2(ed.x, __float_as_int(dis[ed.x] * dis[ed.y]));
    }
}

// ---------------- GEMM: out[n,128] = A[n,128] @ W[128,128]; dual-store f32 + f16 ----------------
__global__ __launch_bounds__(256) void k_gemm128(const float* __restrict__ A,
                                                 const float* __restrict__ W,
                                                 float* __restrict__ out,
                                                 __half* __restrict__ out16, int n) {
    __shared__ float As[32][64];
    __shared__ float Ws[32][128];
    int tid = threadIdx.x;
    int row0b = blockIdx.x * 64;
    int tx = tid & 31, ty = tid >> 5;
    int col0 = tx * 4, r0 = ty * 8;
    float4 acc[8];
#pragma unroll
    for (int i = 0; i < 8; ++i) acc[i] = make_float4(0.f, 0.f, 0.f, 0.f);

    int sr = tid & 63;
    int sq = (tid >> 6) * 4;
    int grow = row0b + sr;

    for (int kc = 0; kc < 128; kc += 32) {
#pragma unroll
        for (int j = 0; j < 2; ++j) {
            int qk = sq + j * 16;
            float4 v = make_float4(0.f, 0.f, 0.f, 0.f);
            if (grow < n) v = *(const float4*)(A + (size_t)grow * FEAT + kc + qk);
            As[qk + 0][sr] = v.x; As[qk + 1][sr] = v.y;
            As[qk + 2][sr] = v.z; As[qk + 3][sr] = v.w;
        }
#pragma unroll
        for (int j = 0; j < 4; ++j) {
            int idx = tid + j * 256;
            int wk = idx >> 5;
            int wc = (idx & 31) * 4;
            *(float4*)&Ws[wk][wc] = *(const float4*)(W + (size_t)(kc + wk) * 128 + wc);
        }
        __syncthreads();
#pragma unroll
        for (int k = 0; k < 32; ++k) {
            float4 w = *(float4*)&Ws[k][col0];
            float a[8];
            *(float4*)&a[0] = *(float4*)&As[k][r0];
            *(float4*)&a[4] = *(float4*)&As[k][r0 + 4];
#pragma unroll
            for (int i = 0; i < 8; ++i) {
                acc[i].x += a[i] * w.x;
                acc[i].y += a[i] * w.y;
                acc[i].z += a[i] * w.z;
                acc[i].w += a[i] * w.w;
            }
        }
        __syncthreads();
    }
#pragma unroll
    for (int i = 0; i < 8; ++i) {
        int row = row0b + r0 + i;
        if (row < n) {
            *(float4*)(out + (size_t)row * 128 + col0) = acc[i];
            half4 h;
            h.lo = __floats2half2_rn(acc[i].x, acc[i].y);
            h.hi = __floats2half2_rn(acc[i].z, acc[i].w);
            *(half4*)(out16 + (size_t)row * 128 + col0) = h;
        }
    }
}

// ---------------- head GEMM: [mu|ls] = A @ [Wmu|Wls] + [bmu|bls] ----------------
__global__ __launch_bounds__(256) void k_gemm_head(const float* __restrict__ A,
                                                   const float* __restrict__ Wmu,
                                                   const float* __restrict__ Wls,
                                                   const float* __restrict__ bmu,
                                                   const float* __restrict__ bls,
                                                   float* __restrict__ mu,
                                                   float* __restrict__ ls, int n) {
    __shared__ float As[32][64];
    __shared__ float Ws[32][128];
    int tid = threadIdx.x;
    int row0b = blockIdx.x * 64;
    int tx = tid & 31, ty = tid >> 5;
    int col0 = tx * 4, r0 = ty * 8;
    float4 acc[8];
#pragma unroll
    for (int i = 0; i < 8; ++i) acc[i] = make_float4(0.f, 0.f, 0.f, 0.f);

    int sr = tid & 63;
    int sq = (tid >> 6) * 4;
    int grow = row0b + sr;

    for (int kc = 0; kc < 128; kc += 32) {
#pragma unroll
        for (int j = 0; j < 2; ++j) {
            int qk = sq + j * 16;
            float4 v = make_float4(0.f, 0.f, 0.f, 0.f);
            if (grow < n) v = *(const float4*)(A + (size_t)grow * FEAT + kc + qk);
            As[qk + 0][sr] = v.x; As[qk + 1][sr] = v.y;
            As[qk + 2][sr] = v.z; As[qk + 3][sr] = v.w;
        }
#pragma unroll
        for (int j = 0; j < 4; ++j) {
            int idx = tid + j * 256;
            int wk = idx >> 5;
            int wc = (idx & 31) * 4;
            const float* Wp = (wc < 64) ? (Wmu + (size_t)(kc + wk) * 64 + wc)
                                        : (Wls + (size_t)(kc + wk) * 64 + (wc - 64));
            *(float4*)&Ws[wk][wc] = *(const float4*)Wp;
        }
        __syncthreads();
#pragma unroll
        for (int k = 0; k < 32; ++k) {
            float4 w = *(float4*)&Ws[k][col0];
            float a[8];
            *(float4*)&a[0] = *(float4*)&As[k][r0];
            *(float4*)&a[4] = *(float4*)&As[k][r0 + 4];
#pragma unroll
            for (int i = 0; i < 8; ++i) {
                acc[i].x += a[i] * w.x;
                acc[i].y += a[i] * w.y;
                acc[i].z += a[i] * w.z;
                acc[i].w += a[i] * w.w;
            }
        }
        __syncthreads();
    }
    bool is_mu = (col0 < 64);
    int c = is_mu ? col0 : col0 - 64;
    const float* bp = is_mu ? (bmu + c) : (bls + c);
    float4 b = *(const float4*)bp;
    float* op = is_mu ? mu : ls;
#pragma unroll
    for (int i = 0; i < 8; ++i) {
        int row = row0b + r0 + i;
        if (row < n)
            *(float4*)(op + (size_t)row * 64 + c) =
                make_float4(acc[i].x + b.x, acc[i].y + b.y, acc[i].z + b.z, acc[i].w + b.w);
    }
}

// ---------------- aggregation: out = [relu](A_norm @ t + bias), fp16 gathers ----------------
__global__ __launch_bounds__(256) void k_agg(const float* __restrict__ t32,
                                             const __half* __restrict__ t16,
                                             const int* __restrict__ row_ptr,
                                             const int2* __restrict__ csr,
                                             const float* __restrict__ dis,
                                             const float* __restrict__ bias,
                                             float* __restrict__ out,
                                             __half* __restrict__ out16,
                                             int n, int do_relu) {
    int wave = (int)((blockIdx.x * blockDim.x + threadIdx.x) >> 6);
    int lane = threadIdx.x & 63;
    if (wave >= n) return;
    int node = wave;
    float d = dis[node];
    float sw = d * d;
    size_t lo = (size_t)(lane << 1);
    float2 self = *(const float2*)(t32 + (size_t)node * FEAT + lo);
    float2 acc[8];
    acc[0].x = self.x * sw; acc[0].y = self.y * sw;
#pragma unroll
    for (int i = 1; i < 8; ++i) { acc[i].x = 0.f; acc[i].y = 0.f; }
    int e = row_ptr[node], e1 = row_ptr[node + 1];
    for (; e + 8 <= e1; e += 8) {
        int2 c[8];
#pragma unroll
        for (int i = 0; i < 8; ++i) c[i] = csr[e + i];
        __half2 hv[8];
#pragma unroll
        for (int i = 0; i < 8; ++i)
            hv[i] = *((const __half2*)(t16 + ((size_t)c[i].x << 7)) + lane);
#pragma unroll
        for (int i = 0; i < 8; ++i) {
            float w = __int_as_float(c[i].y);
            float2 v = __half22float2(hv[i]);
            acc[i].x += w * v.x;
            acc[i].y += w * v.y;
        }
    }
    for (; e + 4 <= e1; e += 4) {
        int2 c[4];
#pragma unroll
        for (int i = 0; i < 4; ++i) c[i] = csr[e + i];
#pragma unroll
        for (int i = 0; i < 4; ++i) {
            float w = __int_as_float(c[i].y);
            float2 v = __half22float2(*((const __half2*)(t16 + ((size_t)c[i].x << 7)) + lane));
            acc[i].x += w * v.x;
            acc[i].y += w * v.y;
        }
    }
    for (; e < e1; ++e) {
        int2 c0 = csr[e];
        float w0 = __int_as_float(c0.y);
        float2 v0 = __half22float2(*((const __half2*)(t16 + ((size_t)c0.x << 7)) + lane));
        acc[0].x += w0 * v0.x; acc[0].y += w0 * v0.y;
    }
#pragma unroll
    for (int i = 1; i < 8; ++i) { acc[0].x += acc[i].x; acc[0].y += acc[i].y; }
    if (bias) {
        acc[0].x += bias[lane << 1];
        acc[0].y += bias[(lane << 1) + 1];
    }
    if (do_relu) {
        acc[0].x = fmaxf(acc[0].x, 0.f);
        acc[0].y = fmaxf(acc[0].y, 0.f);
    }
    *(float2*)(out + (size_t)node * FEAT + lo) = acc[0];
    if (out16)
        *((__half2*)(out16 + (size_t)node * FEAT) + lane) = __floats2half2_rn(acc[0].x, acc[0].y);
}

extern "C" void kernel_launch(void* const* d_in, const int* in_sizes, int n_in,
                              void* d_out, int out_size, void* d_ws, size_t ws_size,
                              hipStream_t stream) {
    const float* x   = (const float*)d_in[0];
    const int*   ei  = (const int*)d_in[1];
    const float* W1  = (const float*)d_in[2];
    const float* b1  = (const float*)d_in[3];
    const float* W2  = (const float*)d_in[4];
    const float* b2  = (const float*)d_in[5];
    const float* W3  = (const float*)d_in[6];
    const float* b3  = (const float*)d_in[7];
    const float* Wmu = (const float*)d_in[8];
    const float* bmu = (const float*)d_in[9];
    const float* Wls = (const float*)d_in[10];
    const float* bls = (const float*)d_in[11];

    int n = in_sizes[0] / FEAT;    // 50000
    int E = in_sizes[1] / 2;       // 1,600,000

    char* ws = (char*)d_ws;
    size_t off = 0;
    auto alloc = [&](size_t bytes) {
        void* p = ws + off;
        off = (off + bytes + 255) & ~(size_t)255;
        return p;
    };
    float*  Bt      = (float*)alloc((size_t)n * FEAT * 4);
    float*  Bh      = (float*)alloc((size_t)n * FEAT * 4);
    __half* Bt16    = (__half*)alloc((size_t)n * FEAT * 2);
    __half* Bh16    = (__half*)alloc((size_t)n * FEAT * 2);
    float*  dis     = (float*)alloc((size_t)n * 4);
    int*    row_ptr = (int*)alloc((size_t)(n + 1) * 4);
    int*    bsum    = (int*)alloc(256 * 4);
    int2*   csr     = (int2*)alloc((size_t)E * 8);

    int BL  = (E + CHUNK - 1) / CHUNK;     // 391 edge blocks
    int lenh = 256 * BL;                   // histogram table size
    int*    gh    = (int*)alloc((size_t)lenh * 4);
    int*    gscan = (int*)alloc((size_t)lenh * 4);
    int2*   ebuf  = (int2*)Bt;             // overlay: Bt not live until first GEMM

    int NBK = (n + 255) >> BKT_SHIFT;      // 196 buckets
    int nbs = (lenh + 511) / 512;          // scan blocks (<=256)

    k_bhist<<<BL, 256, 0, stream>>>(ei + E, E, BL, gh);
    k_s1<<<nbs, 256, 0, stream>>>(gh, lenh, bsum);
    k_s2<<<1, 256, 0, stream>>>(bsum, nbs);
    k_s3<<<nbs, 256, 0, stream>>>(gh, lenh, bsum, gscan);
    k_bscatter<<<BL, 256, 0, stream>>>(ei, E, BL, gscan, ebuf);
    k_bdeg<<<NBK, 256, 0, stream>>>(ebuf, gscan, BL, n, E, row_ptr, dis);
    k_bfill<<<NBK, 256, 0, stream>>>(ebuf, gscan, BL, n, E, row_ptr, dis, csr);

    int gb = (n + 63) / 64;
    int ab = (n + 3) / 4;
    float* mu = (float*)d_out;
    float* ls = (float*)d_out + (size_t)n * 64;

    k_gemm128<<<gb, 256, 0, stream>>>(x,  W1, Bt, Bt16, n);
    k_agg<<<ab, 256, 0, stream>>>(Bt, Bt16, row_ptr, csr, dis, b1, Bh, nullptr, n, 1);
    k_gemm128<<<gb, 256, 0, stream>>>(Bh, W2, Bt, Bt16, n);
    k_agg<<<ab, 256, 0, stream>>>(Bt, Bt16, row_ptr, csr, dis, b2, Bh, nullptr, n, 1);
    k_gemm128<<<gb, 256, 0, stream>>>(Bh, W3, Bt, Bt16, n);
    // h3: dual-store so the shared final aggregation can gather fp16
    k_agg<<<ab, 256, 0, stream>>>(Bt, Bt16, row_ptr, csr, dis, b3, Bh, Bh16, n, 1);
    // g = A_norm @ h3 (shared by both heads; aggregation is linear)
    k_agg<<<ab, 256, 0, stream>>>(Bh, Bh16, row_ptr, csr, dis, nullptr, Bt, nullptr, n, 0);
    k_gemm_head<<<gb, 256, 0, stream>>>(Bt, Wmu, Wls, bmu, bls, mu, ls, n);
}